// Round 4
// baseline (619.460 us; speedup 1.0000x reference)
//
#include <hip/hip_runtime.h>
#include <hip/hip_bf16.h>

// ---------------------------------------------------------------------------
// GIN multi-task forward on MI355X.
// R4: gather rewrite — cooperative index load (1 coalesced csr_src load per
// 32 edges, __shfl broadcast) + 8-deep independent row loads; non-temporal
// store of gather output (keep x rows L2-resident); XCD-partitioned hist.
// ---------------------------------------------------------------------------

#define IN_DIM 128
#define NPART 8          // one partition per XCD

typedef float f32x4 __attribute__((ext_vector_type(4)));

// ---------------- CSR build ------------------------------------------------

// XCD-partitioned histogram: block b counts only dsts in partition (b & 7).
__global__ __launch_bounds__(256) void hist_part_kernel(
    const int* __restrict__ dst, int* __restrict__ counts,
    int n_edges, int n_nodes)
{
    const int p      = blockIdx.x & (NPART - 1);
    const int chunk  = blockIdx.x >> 3;
    const int pstart = (int)(((long long)n_nodes * p)       / NPART);
    const int pend   = (int)(((long long)n_nodes * (p + 1)) / NPART);

    int e0 = chunk * (256 * 4) + threadIdx.x * 4;
    if (e0 >= n_edges) return;
    if (e0 + 3 < n_edges) {
        int4 d = *(const int4*)(dst + e0);
        if (d.x >= pstart && d.x < pend) atomicAdd(&counts[d.x], 1);
        if (d.y >= pstart && d.y < pend) atomicAdd(&counts[d.y], 1);
        if (d.z >= pstart && d.z < pend) atomicAdd(&counts[d.z], 1);
        if (d.w >= pstart && d.w < pend) atomicAdd(&counts[d.w], 1);
    } else {
        for (int e = e0; e < n_edges; ++e) {
            int d = dst[e];
            if (d >= pstart && d < pend) atomicAdd(&counts[d], 1);
        }
    }
}

// phase A: per-block (256 elems) totals
__global__ __launch_bounds__(256) void scan_phaseA(
    const int* __restrict__ counts, int* __restrict__ block_sums, int n)
{
    __shared__ int s[256];
    int i = blockIdx.x * 256 + threadIdx.x;
    s[threadIdx.x] = (i < n) ? counts[i] : 0;
    __syncthreads();
    for (int off = 128; off > 0; off >>= 1) {
        if (threadIdx.x < off) s[threadIdx.x] += s[threadIdx.x + off];
        __syncthreads();
    }
    if (threadIdx.x == 0) block_sums[blockIdx.x] = s[0];
}

// phase B: single-block exclusive scan of block sums (nb <= 256)
__global__ __launch_bounds__(256) void scan_phaseB(int* __restrict__ block_sums, int nb)
{
    __shared__ int s[256];
    int v = (threadIdx.x < nb) ? block_sums[threadIdx.x] : 0;
    s[threadIdx.x] = v;
    __syncthreads();
    for (int off = 1; off < 256; off <<= 1) {
        int t = (threadIdx.x >= off) ? s[threadIdx.x - off] : 0;
        __syncthreads();
        s[threadIdx.x] += t;
        __syncthreads();
    }
    if (threadIdx.x < nb) block_sums[threadIdx.x] = s[threadIdx.x] - v;  // exclusive
}

// phase C: per-block exclusive scan + block offset -> row_start AND cursor
__global__ __launch_bounds__(256) void scan_phaseC(
    const int* __restrict__ counts, const int* __restrict__ block_sums,
    int* __restrict__ row_start, int* __restrict__ cursor, int n, int n_edges)
{
    __shared__ int s[256];
    int i = blockIdx.x * 256 + threadIdx.x;
    int v = (i < n) ? counts[i] : 0;
    s[threadIdx.x] = v;
    __syncthreads();
    for (int off = 1; off < 256; off <<= 1) {
        int t = (threadIdx.x >= off) ? s[threadIdx.x - off] : 0;
        __syncthreads();
        s[threadIdx.x] += t;
        __syncthreads();
    }
    if (i < n) {
        int rs = s[threadIdx.x] - v + block_sums[blockIdx.x];
        row_start[i] = rs;
        cursor[i] = rs;
    }
    if (blockIdx.x == 0 && threadIdx.x == 0) row_start[n] = n_edges;
}

// XCD-partitioned fill: block b handles partition p = b & 7, edge chunk b >> 3.
__global__ __launch_bounds__(256) void fill_part_kernel(
    const int* __restrict__ src, const int* __restrict__ dst,
    int* __restrict__ cursor, int* __restrict__ csr_src,
    int n_edges, int n_nodes)
{
    const int p      = blockIdx.x & (NPART - 1);
    const int chunk  = blockIdx.x >> 3;
    const int pstart = (int)(((long long)n_nodes * p)       / NPART);
    const int pend   = (int)(((long long)n_nodes * (p + 1)) / NPART);

    int e0 = chunk * (256 * 4) + threadIdx.x * 4;
    if (e0 >= n_edges) return;
    if (e0 + 3 < n_edges) {
        int4 d = *(const int4*)(dst + e0);
        int4 s = *(const int4*)(src + e0);
        if (d.x >= pstart && d.x < pend) csr_src[atomicAdd(&cursor[d.x], 1)] = s.x;
        if (d.y >= pstart && d.y < pend) csr_src[atomicAdd(&cursor[d.y], 1)] = s.y;
        if (d.z >= pstart && d.z < pend) csr_src[atomicAdd(&cursor[d.z], 1)] = s.z;
        if (d.w >= pstart && d.w < pend) csr_src[atomicAdd(&cursor[d.w], 1)] = s.w;
    } else {
        for (int e = e0; e < n_edges; ++e) {
            int d = dst[e];
            if (d >= pstart && d < pend) csr_src[atomicAdd(&cursor[d], 1)] = src[e];
        }
    }
}

// ---------------- gather aggregation (fused x + sum) -----------------------
// One 32-lane group per destination node; lane f handles float4 #f of the
// 128-float row. Indices loaded cooperatively: lane l loads csr_src[base+l]
// (one coalesced load per 32 edges), broadcast via __shfl. Row loads are
// issued 8-deep with no index->row dependent hop inside the loop.
__global__ __launch_bounds__(256) void gather_agg_kernel(
    const float4* __restrict__ x4, const int* __restrict__ row_start,
    const int* __restrict__ csr_src, float4* __restrict__ out, int n_nodes)
{
    int t = blockIdx.x * 256 + threadIdx.x;
    int node = t >> 5;
    int lane = t & 31;
    if (node >= n_nodes) return;
    int lo = row_start[node];
    int hi = row_start[node + 1];

    float4 acc = x4[(size_t)node * 32 + lane];  // fused self term

    for (int base = lo; base < hi; base += 32) {
        int nb = hi - base;
        if (nb > 32) nb = 32;
        int myidx = (lane < nb) ? csr_src[base + lane] : 0;

        int j = 0;
        for (; j + 7 < nb; j += 8) {
            int i0 = __shfl(myidx, j + 0, 32);
            int i1 = __shfl(myidx, j + 1, 32);
            int i2 = __shfl(myidx, j + 2, 32);
            int i3 = __shfl(myidx, j + 3, 32);
            int i4 = __shfl(myidx, j + 4, 32);
            int i5 = __shfl(myidx, j + 5, 32);
            int i6 = __shfl(myidx, j + 6, 32);
            int i7 = __shfl(myidx, j + 7, 32);
            float4 v0 = x4[(size_t)i0 * 32 + lane];
            float4 v1 = x4[(size_t)i1 * 32 + lane];
            float4 v2 = x4[(size_t)i2 * 32 + lane];
            float4 v3 = x4[(size_t)i3 * 32 + lane];
            float4 v4 = x4[(size_t)i4 * 32 + lane];
            float4 v5 = x4[(size_t)i5 * 32 + lane];
            float4 v6 = x4[(size_t)i6 * 32 + lane];
            float4 v7 = x4[(size_t)i7 * 32 + lane];
            acc.x += ((v0.x + v1.x) + (v2.x + v3.x)) + ((v4.x + v5.x) + (v6.x + v7.x));
            acc.y += ((v0.y + v1.y) + (v2.y + v3.y)) + ((v4.y + v5.y) + (v6.y + v7.y));
            acc.z += ((v0.z + v1.z) + (v2.z + v3.z)) + ((v4.z + v5.z) + (v6.z + v7.z));
            acc.w += ((v0.w + v1.w) + (v2.w + v3.w)) + ((v4.w + v5.w) + (v6.w + v7.w));
        }
        for (; j < nb; ++j) {
            int i0 = __shfl(myidx, j, 32);
            float4 v0 = x4[(size_t)i0 * 32 + lane];
            acc.x += v0.x; acc.y += v0.y; acc.z += v0.z; acc.w += v0.w;
        }
    }

    // streaming output, read once by the next GEMM: keep it out of L2
    f32x4 o = {acc.x, acc.y, acc.z, acc.w};
    __builtin_nontemporal_store(o, (f32x4*)(out + (size_t)node * 32 + lane));
}

// ---------------- tiled SGEMM (fp32 vector ALU) ----------------------------
// C[M x 128] = relu(A @ W[128 x 128] + bias). 256 thr, 64x128 tile, 8x4/thread.
__global__ __launch_bounds__(256) void gemm128_kernel(
    const float* __restrict__ A1, const float* __restrict__ W,
    const float* __restrict__ bias, float* __restrict__ C, int M)
{
    __shared__ float As[16][68];
    __shared__ float Bs[16][128];

    const int t  = threadIdx.x;
    const int tx = t & 31;
    const int ty = t >> 5;
    const int row0 = blockIdx.x * 64;

    float acc[8][4];
#pragma unroll
    for (int i = 0; i < 8; ++i)
#pragma unroll
        for (int j = 0; j < 4; ++j) acc[i][j] = 0.f;

    const int arow = t >> 2;
    const int kq   = t & 3;
    const int grow = row0 + arow;
    const int kr   = t >> 5;

    for (int k0 = 0; k0 < IN_DIM; k0 += 16) {
        float4 av = make_float4(0.f, 0.f, 0.f, 0.f);
        if (grow < M)
            av = *(const float4*)(A1 + (size_t)grow * IN_DIM + k0 + kq * 4);
        float4 w0 = *(const float4*)(W + (size_t)(k0 + kr)     * IN_DIM + tx * 4);
        float4 w1 = *(const float4*)(W + (size_t)(k0 + kr + 8) * IN_DIM + tx * 4);

        As[kq * 4 + 0][arow] = av.x;
        As[kq * 4 + 1][arow] = av.y;
        As[kq * 4 + 2][arow] = av.z;
        As[kq * 4 + 3][arow] = av.w;
        *(float4*)&Bs[kr][tx * 4]     = w0;
        *(float4*)&Bs[kr + 8][tx * 4] = w1;
        __syncthreads();

#pragma unroll
        for (int kk = 0; kk < 16; ++kk) {
            float4 a0 = *(const float4*)&As[kk][ty * 8];
            float4 a1 = *(const float4*)&As[kk][ty * 8 + 4];
            float4 w  = *(const float4*)&Bs[kk][tx * 4];
            float a[8] = {a0.x, a0.y, a0.z, a0.w, a1.x, a1.y, a1.z, a1.w};
            float wv[4] = {w.x, w.y, w.z, w.w};
#pragma unroll
            for (int i = 0; i < 8; ++i)
#pragma unroll
                for (int j = 0; j < 4; ++j)
                    acc[i][j] = fmaf(a[i], wv[j], acc[i][j]);
        }
        __syncthreads();
    }

    float4 bv = *(const float4*)(bias + tx * 4);
    float b[4] = {bv.x, bv.y, bv.z, bv.w};
#pragma unroll
    for (int i = 0; i < 8; ++i) {
        int r = row0 + ty * 8 + i;
        if (r < M) {
            float4 o;
            o.x = fmaxf(acc[i][0] + b[0], 0.f);
            o.y = fmaxf(acc[i][1] + b[1], 0.f);
            o.z = fmaxf(acc[i][2] + b[2], 0.f);
            o.w = fmaxf(acc[i][3] + b[3], 0.f);
            *(float4*)(C + (size_t)r * IN_DIM + tx * 4) = o;
        }
    }
}

// ---------------- pool + heads ---------------------------------------------

__device__ __forceinline__ int lower_bound_i(const int* __restrict__ a, int n, int v) {
    int lo = 0, hi = n;
    while (lo < hi) {
        int mid = (lo + hi) >> 1;
        if (a[mid] < v) lo = mid + 1; else hi = mid;
    }
    return lo;
}

__global__ __launch_bounds__(128) void pool_kernel(
    const float* __restrict__ h, const int* __restrict__ batch,
    float* __restrict__ pooled, int n_nodes, int n_graphs)
{
    int g = blockIdx.x;
    int lo = lower_bound_i(batch, n_nodes, g);
    int hi = lower_bound_i(batch, n_nodes, g + 1);
    int j = threadIdx.x;
    float acc = 0.f;
    for (int i = lo; i < hi; ++i)
        acc += h[(size_t)i * IN_DIM + j];
    float cnt = (float)(hi - lo);
    pooled[(size_t)g * IN_DIM + j] = acc / fmaxf(cnt, 1.0f);
}

__global__ __launch_bounds__(64) void head_kernel(
    const float* __restrict__ pooled,
    const float* __restrict__ Ws,  const float* __restrict__ bs,
    const float* __restrict__ WlS, const float* __restrict__ blS,
    const float* __restrict__ WlP, const float* __restrict__ blP,
    const float* __restrict__ WnR, const float* __restrict__ bnR,
    float* __restrict__ out, int n_graphs)
{
    int g = blockIdx.x;
    int j = threadIdx.x;
    const float* p = pooled + (size_t)g * IN_DIM;
    float acc = bs[j];
#pragma unroll 8
    for (int k = 0; k < IN_DIM; ++k)
        acc = fmaf(p[k], Ws[k * 64 + j], acc);
    float gj = fmaxf(acc, 0.f);
    float s1 = gj * WlS[j];
    float s2 = gj * WlP[j];
    float s3 = gj * WnR[j];
#pragma unroll
    for (int off = 32; off > 0; off >>= 1) {
        s1 += __shfl_down(s1, off);
        s2 += __shfl_down(s2, off);
        s3 += __shfl_down(s3, off);
    }
    if (j == 0) {
        out[g]                = s1 + blS[0];
        out[n_graphs + g]     = s2 + blP[0];
        out[2 * n_graphs + g] = s3 + bnR[0];
    }
}

// ---------------- launch ---------------------------------------------------

extern "C" void kernel_launch(void* const* d_in, const int* in_sizes, int n_in,
                              void* d_out, int out_size, void* d_ws, size_t ws_size,
                              hipStream_t stream)
{
    const float* x   = (const float*)d_in[0];
    const int*   ei  = (const int*)d_in[1];
    const int*   bat = (const int*)d_in[2];
    const float* W1a = (const float*)d_in[3];
    const float* b1a = (const float*)d_in[4];
    const float* W1b = (const float*)d_in[5];
    const float* b1b = (const float*)d_in[6];
    const float* W2a = (const float*)d_in[7];
    const float* b2a = (const float*)d_in[8];
    const float* W2b = (const float*)d_in[9];
    const float* b2b = (const float*)d_in[10];
    const float* Ws  = (const float*)d_in[11];
    const float* bs  = (const float*)d_in[12];
    const float* WlS = (const float*)d_in[13];
    const float* blS = (const float*)d_in[14];
    const float* WlP = (const float*)d_in[15];
    const float* blP = (const float*)d_in[16];
    const float* WnR = (const float*)d_in[17];
    const float* bnR = (const float*)d_in[18];

    const int n_nodes  = in_sizes[0] / IN_DIM;
    const int n_edges  = in_sizes[1] / 2;
    const int n_graphs = out_size / 3;
    const int* src = ei;
    const int* dst = ei + n_edges;

    const size_t node_elems   = (size_t)n_nodes * IN_DIM;
    const size_t pooled_elems = (size_t)n_graphs * IN_DIM;

    float* h1     = (float*)d_ws;
    float* buf2   = h1   + node_elems;
    float* bufA   = buf2 + node_elems;          // gather output (x + agg)
    float* pooled = bufA + node_elems;
    int* row_start = (int*)(pooled + pooled_elems);   // n_nodes + 1
    int* cursor    = row_start + (n_nodes + 1);       // n_nodes (also histogram)
    int* csr_src   = cursor + n_nodes;                // n_edges

    const int eblocks4 = (n_edges + 1023) / 1024;     // 4 edges/thread
    const int nblocks256 = (n_nodes + 255) / 256;     // <=256: scan ok
    const int gatherblocks = (int)(((size_t)n_nodes * 32 + 255) / 256);
    const int gemmblocks = (n_nodes + 63) / 64;
    const int partblocks = NPART * eblocks4;

    // ---- CSR build (dst-sorted adjacency) ----
    hipMemsetAsync(cursor, 0, (size_t)n_nodes * sizeof(int), stream);
    hist_part_kernel<<<partblocks, 256, 0, stream>>>(dst, cursor, n_edges, n_nodes);
    scan_phaseA<<<nblocks256, 256, 0, stream>>>(cursor, csr_src /*scratch*/, n_nodes);
    scan_phaseB<<<1, 256, 0, stream>>>(csr_src, nblocks256);
    scan_phaseC<<<nblocks256, 256, 0, stream>>>(cursor, csr_src, row_start,
                                                cursor, n_nodes, n_edges);
    fill_part_kernel<<<partblocks, 256, 0, stream>>>(src, dst, cursor, csr_src,
                                                     n_edges, n_nodes);

    // ---- layer 1 ----
    gather_agg_kernel<<<gatherblocks, 256, 0, stream>>>(
        (const float4*)x, row_start, csr_src, (float4*)bufA, n_nodes);
    gemm128_kernel<<<gemmblocks, 256, 0, stream>>>(bufA, W1a, b1a, h1, n_nodes);
    gemm128_kernel<<<gemmblocks, 256, 0, stream>>>(h1,   W1b, b1b, buf2, n_nodes);

    // ---- layer 2 ----
    gather_agg_kernel<<<gatherblocks, 256, 0, stream>>>(
        (const float4*)buf2, row_start, csr_src, (float4*)bufA, n_nodes);
    gemm128_kernel<<<gemmblocks, 256, 0, stream>>>(bufA, W2a, b2a, h1, n_nodes);
    gemm128_kernel<<<gemmblocks, 256, 0, stream>>>(h1,   W2b, b2b, buf2, n_nodes);

    // ---- pool + heads ----
    pool_kernel<<<n_graphs, 128, 0, stream>>>(buf2, bat, pooled, n_nodes, n_graphs);
    head_kernel<<<n_graphs, 64, 0, stream>>>(pooled, Ws, bs, WlS, blS, WlP, blP,
                                             WnR, bnR, (float*)d_out, n_graphs);
}

// Round 5
// 527.017 us; speedup vs baseline: 1.1754x; 1.1754x over previous
//
#include <hip/hip_runtime.h>
#include <hip/hip_bf16.h>

// ---------------------------------------------------------------------------
// GIN multi-task forward on MI355X.
// R5: bf16 neighbor-gather. A per-call RNE convert produces a 12.8 MB bf16
// mirror of node features; gather reads 256 B/row (16 lanes x 16 B) instead
// of 512 B, halving the L2-miss-path traffic that bounds the gather (R4
// showed 353 MB FETCH @ 3.5 TB/s; issue-depth changes were neutral).
// Self term + accumulation stay fp32. bf16 mirrors alias h1 (dead there).
// ---------------------------------------------------------------------------

#define IN_DIM 128
#define NPART 8          // one partition per XCD

typedef float f32x4 __attribute__((ext_vector_type(4)));

// ---------------- fp32 -> bf16 convert (RNE), 8 elems/thread ---------------

__global__ __launch_bounds__(256) void f32_to_bf16_kernel(
    const float4* __restrict__ in, uint4* __restrict__ out, int n8)
{
    int i = blockIdx.x * 256 + threadIdx.x;
    if (i >= n8) return;
    float4 a = in[i * 2];
    float4 b = in[i * 2 + 1];
    const float* v = (const float*)&a;
    const float* w = (const float*)&b;
    unsigned r[4];
#pragma unroll
    for (int k = 0; k < 2; ++k) {
        const float* p = k ? w : v;
#pragma unroll
        for (int j = 0; j < 2; ++j) {
            unsigned ux = __float_as_uint(p[j * 2]);
            unsigned uy = __float_as_uint(p[j * 2 + 1]);
            unsigned tx = ux + 0x7fffu + ((ux >> 16) & 1u);
            unsigned ty = uy + 0x7fffu + ((uy >> 16) & 1u);
            r[k * 2 + j] = (tx >> 16) | (ty & 0xffff0000u);
        }
    }
    out[i] = make_uint4(r[0], r[1], r[2], r[3]);
}

// ---------------- CSR build ------------------------------------------------

__global__ __launch_bounds__(256) void hist_part_kernel(
    const int* __restrict__ dst, int* __restrict__ counts,
    int n_edges, int n_nodes)
{
    const int p      = blockIdx.x & (NPART - 1);
    const int chunk  = blockIdx.x >> 3;
    const int pstart = (int)(((long long)n_nodes * p)       / NPART);
    const int pend   = (int)(((long long)n_nodes * (p + 1)) / NPART);

    int e0 = chunk * (256 * 4) + threadIdx.x * 4;
    if (e0 >= n_edges) return;
    if (e0 + 3 < n_edges) {
        int4 d = *(const int4*)(dst + e0);
        if (d.x >= pstart && d.x < pend) atomicAdd(&counts[d.x], 1);
        if (d.y >= pstart && d.y < pend) atomicAdd(&counts[d.y], 1);
        if (d.z >= pstart && d.z < pend) atomicAdd(&counts[d.z], 1);
        if (d.w >= pstart && d.w < pend) atomicAdd(&counts[d.w], 1);
    } else {
        for (int e = e0; e < n_edges; ++e) {
            int d = dst[e];
            if (d >= pstart && d < pend) atomicAdd(&counts[d], 1);
        }
    }
}

__global__ __launch_bounds__(256) void scan_phaseA(
    const int* __restrict__ counts, int* __restrict__ block_sums, int n)
{
    __shared__ int s[256];
    int i = blockIdx.x * 256 + threadIdx.x;
    s[threadIdx.x] = (i < n) ? counts[i] : 0;
    __syncthreads();
    for (int off = 128; off > 0; off >>= 1) {
        if (threadIdx.x < off) s[threadIdx.x] += s[threadIdx.x + off];
        __syncthreads();
    }
    if (threadIdx.x == 0) block_sums[blockIdx.x] = s[0];
}

__global__ __launch_bounds__(256) void scan_phaseB(int* __restrict__ block_sums, int nb)
{
    __shared__ int s[256];
    int v = (threadIdx.x < nb) ? block_sums[threadIdx.x] : 0;
    s[threadIdx.x] = v;
    __syncthreads();
    for (int off = 1; off < 256; off <<= 1) {
        int t = (threadIdx.x >= off) ? s[threadIdx.x - off] : 0;
        __syncthreads();
        s[threadIdx.x] += t;
        __syncthreads();
    }
    if (threadIdx.x < nb) block_sums[threadIdx.x] = s[threadIdx.x] - v;  // exclusive
}

__global__ __launch_bounds__(256) void scan_phaseC(
    const int* __restrict__ counts, const int* __restrict__ block_sums,
    int* __restrict__ row_start, int* __restrict__ cursor, int n, int n_edges)
{
    __shared__ int s[256];
    int i = blockIdx.x * 256 + threadIdx.x;
    int v = (i < n) ? counts[i] : 0;
    s[threadIdx.x] = v;
    __syncthreads();
    for (int off = 1; off < 256; off <<= 1) {
        int t = (threadIdx.x >= off) ? s[threadIdx.x - off] : 0;
        __syncthreads();
        s[threadIdx.x] += t;
        __syncthreads();
    }
    if (i < n) {
        int rs = s[threadIdx.x] - v + block_sums[blockIdx.x];
        row_start[i] = rs;
        cursor[i] = rs;
    }
    if (blockIdx.x == 0 && threadIdx.x == 0) row_start[n] = n_edges;
}

__global__ __launch_bounds__(256) void fill_part_kernel(
    const int* __restrict__ src, const int* __restrict__ dst,
    int* __restrict__ cursor, int* __restrict__ csr_src,
    int n_edges, int n_nodes)
{
    const int p      = blockIdx.x & (NPART - 1);
    const int chunk  = blockIdx.x >> 3;
    const int pstart = (int)(((long long)n_nodes * p)       / NPART);
    const int pend   = (int)(((long long)n_nodes * (p + 1)) / NPART);

    int e0 = chunk * (256 * 4) + threadIdx.x * 4;
    if (e0 >= n_edges) return;
    if (e0 + 3 < n_edges) {
        int4 d = *(const int4*)(dst + e0);
        int4 s = *(const int4*)(src + e0);
        if (d.x >= pstart && d.x < pend) csr_src[atomicAdd(&cursor[d.x], 1)] = s.x;
        if (d.y >= pstart && d.y < pend) csr_src[atomicAdd(&cursor[d.y], 1)] = s.y;
        if (d.z >= pstart && d.z < pend) csr_src[atomicAdd(&cursor[d.z], 1)] = s.z;
        if (d.w >= pstart && d.w < pend) csr_src[atomicAdd(&cursor[d.w], 1)] = s.w;
    } else {
        for (int e = e0; e < n_edges; ++e) {
            int d = dst[e];
            if (d >= pstart && d < pend) csr_src[atomicAdd(&cursor[d], 1)] = src[e];
        }
    }
}

// ---------------- gather aggregation (bf16 neighbors, fp32 self/acc) -------
// 16 lanes per node; lane f handles elements [f*8, f*8+8). Neighbor row read
// as one uint4 (8 bf16, 16 B) per lane; bf16->fp32 via shift/mask.
__device__ __forceinline__ void add_row8(float acc[8], uint4 r) {
    union { unsigned u; float f; } c;
    c.u = r.x << 16;         acc[0] += c.f;
    c.u = r.x & 0xffff0000u; acc[1] += c.f;
    c.u = r.y << 16;         acc[2] += c.f;
    c.u = r.y & 0xffff0000u; acc[3] += c.f;
    c.u = r.z << 16;         acc[4] += c.f;
    c.u = r.z & 0xffff0000u; acc[5] += c.f;
    c.u = r.w << 16;         acc[6] += c.f;
    c.u = r.w & 0xffff0000u; acc[7] += c.f;
}

__global__ __launch_bounds__(256) void gather_agg_bf16_kernel(
    const float4* __restrict__ xf,   // fp32 rows (self term), 32 float4/row
    const uint4* __restrict__ xb,    // bf16 rows, 16 uint4/row
    const int* __restrict__ row_start, const int* __restrict__ csr_src,
    float4* __restrict__ out, int n_nodes)
{
    int t = blockIdx.x * 256 + threadIdx.x;
    int node = t >> 4;
    int lane = t & 15;
    if (node >= n_nodes) return;
    int lo = row_start[node];
    int hi = row_start[node + 1];

    float4 a0 = xf[(size_t)node * 32 + lane * 2];
    float4 a1 = xf[(size_t)node * 32 + lane * 2 + 1];
    float acc[8] = {a0.x, a0.y, a0.z, a0.w, a1.x, a1.y, a1.z, a1.w};

    int e = lo;
    for (; e + 3 < hi; e += 4) {
        int s0 = csr_src[e];
        int s1 = csr_src[e + 1];
        int s2 = csr_src[e + 2];
        int s3 = csr_src[e + 3];
        uint4 r0 = xb[(size_t)s0 * 16 + lane];
        uint4 r1 = xb[(size_t)s1 * 16 + lane];
        uint4 r2 = xb[(size_t)s2 * 16 + lane];
        uint4 r3 = xb[(size_t)s3 * 16 + lane];
        add_row8(acc, r0);
        add_row8(acc, r1);
        add_row8(acc, r2);
        add_row8(acc, r3);
    }
    for (; e < hi; ++e) {
        uint4 r = xb[(size_t)csr_src[e] * 16 + lane];
        add_row8(acc, r);
    }

    f32x4 o0 = {acc[0], acc[1], acc[2], acc[3]};
    f32x4 o1 = {acc[4], acc[5], acc[6], acc[7]};
    __builtin_nontemporal_store(o0, (f32x4*)(out + (size_t)node * 32 + lane * 2));
    __builtin_nontemporal_store(o1, (f32x4*)(out + (size_t)node * 32 + lane * 2 + 1));
}

// ---------------- tiled SGEMM (fp32 vector ALU) ----------------------------
__global__ __launch_bounds__(256) void gemm128_kernel(
    const float* __restrict__ A1, const float* __restrict__ W,
    const float* __restrict__ bias, float* __restrict__ C, int M)
{
    __shared__ float As[16][68];
    __shared__ float Bs[16][128];

    const int t  = threadIdx.x;
    const int tx = t & 31;
    const int ty = t >> 5;
    const int row0 = blockIdx.x * 64;

    float acc[8][4];
#pragma unroll
    for (int i = 0; i < 8; ++i)
#pragma unroll
        for (int j = 0; j < 4; ++j) acc[i][j] = 0.f;

    const int arow = t >> 2;
    const int kq   = t & 3;
    const int grow = row0 + arow;
    const int kr   = t >> 5;

    for (int k0 = 0; k0 < IN_DIM; k0 += 16) {
        float4 av = make_float4(0.f, 0.f, 0.f, 0.f);
        if (grow < M)
            av = *(const float4*)(A1 + (size_t)grow * IN_DIM + k0 + kq * 4);
        float4 w0 = *(const float4*)(W + (size_t)(k0 + kr)     * IN_DIM + tx * 4);
        float4 w1 = *(const float4*)(W + (size_t)(k0 + kr + 8) * IN_DIM + tx * 4);

        As[kq * 4 + 0][arow] = av.x;
        As[kq * 4 + 1][arow] = av.y;
        As[kq * 4 + 2][arow] = av.z;
        As[kq * 4 + 3][arow] = av.w;
        *(float4*)&Bs[kr][tx * 4]     = w0;
        *(float4*)&Bs[kr + 8][tx * 4] = w1;
        __syncthreads();

#pragma unroll
        for (int kk = 0; kk < 16; ++kk) {
            float4 a0 = *(const float4*)&As[kk][ty * 8];
            float4 a1 = *(const float4*)&As[kk][ty * 8 + 4];
            float4 w  = *(const float4*)&Bs[kk][tx * 4];
            float a[8] = {a0.x, a0.y, a0.z, a0.w, a1.x, a1.y, a1.z, a1.w};
            float wv[4] = {w.x, w.y, w.z, w.w};
#pragma unroll
            for (int i = 0; i < 8; ++i)
#pragma unroll
                for (int j = 0; j < 4; ++j)
                    acc[i][j] = fmaf(a[i], wv[j], acc[i][j]);
        }
        __syncthreads();
    }

    float4 bv = *(const float4*)(bias + tx * 4);
    float b[4] = {bv.x, bv.y, bv.z, bv.w};
#pragma unroll
    for (int i = 0; i < 8; ++i) {
        int r = row0 + ty * 8 + i;
        if (r < M) {
            float4 o;
            o.x = fmaxf(acc[i][0] + b[0], 0.f);
            o.y = fmaxf(acc[i][1] + b[1], 0.f);
            o.z = fmaxf(acc[i][2] + b[2], 0.f);
            o.w = fmaxf(acc[i][3] + b[3], 0.f);
            *(float4*)(C + (size_t)r * IN_DIM + tx * 4) = o;
        }
    }
}

// ---------------- pool + heads ---------------------------------------------

__device__ __forceinline__ int lower_bound_i(const int* __restrict__ a, int n, int v) {
    int lo = 0, hi = n;
    while (lo < hi) {
        int mid = (lo + hi) >> 1;
        if (a[mid] < v) lo = mid + 1; else hi = mid;
    }
    return lo;
}

__global__ __launch_bounds__(128) void pool_kernel(
    const float* __restrict__ h, const int* __restrict__ batch,
    float* __restrict__ pooled, int n_nodes, int n_graphs)
{
    int g = blockIdx.x;
    int lo = lower_bound_i(batch, n_nodes, g);
    int hi = lower_bound_i(batch, n_nodes, g + 1);
    int j = threadIdx.x;
    float acc = 0.f;
    for (int i = lo; i < hi; ++i)
        acc += h[(size_t)i * IN_DIM + j];
    float cnt = (float)(hi - lo);
    pooled[(size_t)g * IN_DIM + j] = acc / fmaxf(cnt, 1.0f);
}

__global__ __launch_bounds__(64) void head_kernel(
    const float* __restrict__ pooled,
    const float* __restrict__ Ws,  const float* __restrict__ bs,
    const float* __restrict__ WlS, const float* __restrict__ blS,
    const float* __restrict__ WlP, const float* __restrict__ blP,
    const float* __restrict__ WnR, const float* __restrict__ bnR,
    float* __restrict__ out, int n_graphs)
{
    int g = blockIdx.x;
    int j = threadIdx.x;
    const float* p = pooled + (size_t)g * IN_DIM;
    float acc = bs[j];
#pragma unroll 8
    for (int k = 0; k < IN_DIM; ++k)
        acc = fmaf(p[k], Ws[k * 64 + j], acc);
    float gj = fmaxf(acc, 0.f);
    float s1 = gj * WlS[j];
    float s2 = gj * WlP[j];
    float s3 = gj * WnR[j];
#pragma unroll
    for (int off = 32; off > 0; off >>= 1) {
        s1 += __shfl_down(s1, off);
        s2 += __shfl_down(s2, off);
        s3 += __shfl_down(s3, off);
    }
    if (j == 0) {
        out[g]                = s1 + blS[0];
        out[n_graphs + g]     = s2 + blP[0];
        out[2 * n_graphs + g] = s3 + bnR[0];
    }
}

// ---------------- launch ---------------------------------------------------

extern "C" void kernel_launch(void* const* d_in, const int* in_sizes, int n_in,
                              void* d_out, int out_size, void* d_ws, size_t ws_size,
                              hipStream_t stream)
{
    const float* x   = (const float*)d_in[0];
    const int*   ei  = (const int*)d_in[1];
    const int*   bat = (const int*)d_in[2];
    const float* W1a = (const float*)d_in[3];
    const float* b1a = (const float*)d_in[4];
    const float* W1b = (const float*)d_in[5];
    const float* b1b = (const float*)d_in[6];
    const float* W2a = (const float*)d_in[7];
    const float* b2a = (const float*)d_in[8];
    const float* W2b = (const float*)d_in[9];
    const float* b2b = (const float*)d_in[10];
    const float* Ws  = (const float*)d_in[11];
    const float* bs  = (const float*)d_in[12];
    const float* WlS = (const float*)d_in[13];
    const float* blS = (const float*)d_in[14];
    const float* WlP = (const float*)d_in[15];
    const float* blP = (const float*)d_in[16];
    const float* WnR = (const float*)d_in[17];
    const float* bnR = (const float*)d_in[18];

    const int n_nodes  = in_sizes[0] / IN_DIM;
    const int n_edges  = in_sizes[1] / 2;
    const int n_graphs = out_size / 3;
    const int* src = ei;
    const int* dst = ei + n_edges;

    const size_t node_elems   = (size_t)n_nodes * IN_DIM;
    const size_t pooled_elems = (size_t)n_graphs * IN_DIM;

    float* h1     = (float*)d_ws;
    float* buf2   = h1   + node_elems;
    float* bufA   = buf2 + node_elems;          // gather output (x + agg)
    float* pooled = bufA + node_elems;
    int* row_start = (int*)(pooled + pooled_elems);   // n_nodes + 1
    int* cursor    = row_start + (n_nodes + 1);       // n_nodes (also histogram)
    int* csr_src   = cursor + n_nodes;                // n_edges

    // bf16 mirror aliases h1: h1 is dead when each convert runs (sequential
    // stream; gather consumes the mirror before the next GEMM writes h1).
    uint4* xb = (uint4*)h1;

    const int eblocks4 = (n_edges + 1023) / 1024;     // 4 edges/thread
    const int nblocks256 = (n_nodes + 255) / 256;
    const int gatherblocks = (int)(((size_t)n_nodes * 16 + 255) / 256);
    const int gemmblocks = (n_nodes + 63) / 64;
    const int partblocks = NPART * eblocks4;
    const int n8 = (int)(node_elems / 8);
    const int cvtblocks = (n8 + 255) / 256;

    // ---- CSR build (dst-sorted adjacency) ----
    hipMemsetAsync(cursor, 0, (size_t)n_nodes * sizeof(int), stream);
    hist_part_kernel<<<partblocks, 256, 0, stream>>>(dst, cursor, n_edges, n_nodes);
    scan_phaseA<<<nblocks256, 256, 0, stream>>>(cursor, csr_src /*scratch*/, n_nodes);
    scan_phaseB<<<1, 256, 0, stream>>>(csr_src, nblocks256);
    scan_phaseC<<<nblocks256, 256, 0, stream>>>(cursor, csr_src, row_start,
                                                cursor, n_nodes, n_edges);
    fill_part_kernel<<<partblocks, 256, 0, stream>>>(src, dst, cursor, csr_src,
                                                     n_edges, n_nodes);

    // ---- layer 1 ----
    f32_to_bf16_kernel<<<cvtblocks, 256, 0, stream>>>((const float4*)x, xb, n8);
    gather_agg_bf16_kernel<<<gatherblocks, 256, 0, stream>>>(
        (const float4*)x, xb, row_start, csr_src, (float4*)bufA, n_nodes);
    gemm128_kernel<<<gemmblocks, 256, 0, stream>>>(bufA, W1a, b1a, h1, n_nodes);
    gemm128_kernel<<<gemmblocks, 256, 0, stream>>>(h1,   W1b, b1b, buf2, n_nodes);

    // ---- layer 2 ----
    f32_to_bf16_kernel<<<cvtblocks, 256, 0, stream>>>((const float4*)buf2, xb, n8);
    gather_agg_bf16_kernel<<<gatherblocks, 256, 0, stream>>>(
        (const float4*)buf2, xb, row_start, csr_src, (float4*)bufA, n_nodes);
    gemm128_kernel<<<gemmblocks, 256, 0, stream>>>(bufA, W2a, b2a, h1, n_nodes);
    gemm128_kernel<<<gemmblocks, 256, 0, stream>>>(h1,   W2b, b2b, buf2, n_nodes);

    // ---- pool + heads ----
    pool_kernel<<<n_graphs, 128, 0, stream>>>(buf2, bat, pooled, n_nodes, n_graphs);
    head_kernel<<<n_graphs, 64, 0, stream>>>(pooled, Ws, bs, WlS, blS, WlP, blP,
                                             WnR, bnR, (float*)d_out, n_graphs);
}

// Round 6
// 503.192 us; speedup vs baseline: 1.2311x; 1.0473x over previous
//
#include <hip/hip_runtime.h>
#include <hip/hip_bf16.h>

// ---------------------------------------------------------------------------
// GIN multi-task forward on MI355X.
// R6: (1) non-temporal edge-list loads in hist/fill (streaming reads were
// evicting the partially-filled csr lines -> 10x write amplification);
// (2) split-bf16 MFMA GEMM (Ah@Wh + Al@Wh + Ah@Wl, fp32-accurate) replacing
// the ~60us fp32 vector-ALU SGEMMs. W pre-converted per call to transposed
// bf16 hi/lo; A converted in-kernel while staging to LDS.
// ---------------------------------------------------------------------------

#define IN_DIM 128
#define NPART 8          // one partition per XCD

typedef float  f32x4  __attribute__((ext_vector_type(4)));
typedef int    i32x4  __attribute__((ext_vector_type(4)));
typedef short  bf16x8 __attribute__((ext_vector_type(8)));

__device__ __forceinline__ unsigned short bf16_rne(float v) {
    unsigned u = __float_as_uint(v);
    unsigned t = u + 0x7fffu + ((u >> 16) & 1u);
    return (unsigned short)(t >> 16);
}

// ---------------- fp32 -> bf16 convert (RNE), 8 elems/thread ---------------

__global__ __launch_bounds__(256) void f32_to_bf16_kernel(
    const float4* __restrict__ in, uint4* __restrict__ out, int n8)
{
    int i = blockIdx.x * 256 + threadIdx.x;
    if (i >= n8) return;
    float4 a = in[i * 2];
    float4 b = in[i * 2 + 1];
    float v[8] = {a.x, a.y, a.z, a.w, b.x, b.y, b.z, b.w};
    unsigned r[4];
#pragma unroll
    for (int j = 0; j < 4; ++j)
        r[j] = (unsigned)bf16_rne(v[j * 2]) | ((unsigned)bf16_rne(v[j * 2 + 1]) << 16);
    out[i] = make_uint4(r[0], r[1], r[2], r[3]);
}

// ---------------- weight convert: W[k][n] fp32 -> Wt_h/Wt_l[n][k] bf16 -----

__global__ __launch_bounds__(256) void conv_weights_kernel(
    const float* __restrict__ W0, const float* __restrict__ W1,
    const float* __restrict__ W2, const float* __restrict__ W3,
    unsigned short* __restrict__ Wh, unsigned short* __restrict__ Wl)
{
    int m   = blockIdx.x >> 6;                       // 64 blocks per matrix
    int idx = (blockIdx.x & 63) * 256 + threadIdx.x; // 0..16383
    const float* W = (m == 0) ? W0 : (m == 1) ? W1 : (m == 2) ? W2 : W3;
    int k = idx >> 7, n = idx & 127;
    float v = W[idx];
    unsigned short hh = bf16_rne(v);
    float hf = __uint_as_float(((unsigned)hh) << 16);
    unsigned short ll = bf16_rne(v - hf);
    Wh[m * 16384 + n * 128 + k] = hh;
    Wl[m * 16384 + n * 128 + k] = ll;
}

// ---------------- CSR build ------------------------------------------------

__global__ __launch_bounds__(256) void hist_part_kernel(
    const int* __restrict__ dst, int* __restrict__ counts,
    int n_edges, int n_nodes)
{
    const int p      = blockIdx.x & (NPART - 1);
    const int chunk  = blockIdx.x >> 3;
    const int pstart = (int)(((long long)n_nodes * p)       / NPART);
    const int pend   = (int)(((long long)n_nodes * (p + 1)) / NPART);

    int e0 = chunk * (256 * 4) + threadIdx.x * 4;
    if (e0 >= n_edges) return;
    if (e0 + 3 < n_edges) {
        i32x4 d = __builtin_nontemporal_load((const i32x4*)(dst + e0));
        if (d.x >= pstart && d.x < pend) atomicAdd(&counts[d.x], 1);
        if (d.y >= pstart && d.y < pend) atomicAdd(&counts[d.y], 1);
        if (d.z >= pstart && d.z < pend) atomicAdd(&counts[d.z], 1);
        if (d.w >= pstart && d.w < pend) atomicAdd(&counts[d.w], 1);
    } else {
        for (int e = e0; e < n_edges; ++e) {
            int d = dst[e];
            if (d >= pstart && d < pend) atomicAdd(&counts[d], 1);
        }
    }
}

__global__ __launch_bounds__(256) void scan_phaseA(
    const int* __restrict__ counts, int* __restrict__ block_sums, int n)
{
    __shared__ int s[256];
    int i = blockIdx.x * 256 + threadIdx.x;
    s[threadIdx.x] = (i < n) ? counts[i] : 0;
    __syncthreads();
    for (int off = 128; off > 0; off >>= 1) {
        if (threadIdx.x < off) s[threadIdx.x] += s[threadIdx.x + off];
        __syncthreads();
    }
    if (threadIdx.x == 0) block_sums[blockIdx.x] = s[0];
}

__global__ __launch_bounds__(256) void scan_phaseB(int* __restrict__ block_sums, int nb)
{
    __shared__ int s[256];
    int v = (threadIdx.x < nb) ? block_sums[threadIdx.x] : 0;
    s[threadIdx.x] = v;
    __syncthreads();
    for (int off = 1; off < 256; off <<= 1) {
        int t = (threadIdx.x >= off) ? s[threadIdx.x - off] : 0;
        __syncthreads();
        s[threadIdx.x] += t;
        __syncthreads();
    }
    if (threadIdx.x < nb) block_sums[threadIdx.x] = s[threadIdx.x] - v;  // exclusive
}

__global__ __launch_bounds__(256) void scan_phaseC(
    const int* __restrict__ counts, const int* __restrict__ block_sums,
    int* __restrict__ row_start, int* __restrict__ cursor, int n, int n_edges)
{
    __shared__ int s[256];
    int i = blockIdx.x * 256 + threadIdx.x;
    int v = (i < n) ? counts[i] : 0;
    s[threadIdx.x] = v;
    __syncthreads();
    for (int off = 1; off < 256; off <<= 1) {
        int t = (threadIdx.x >= off) ? s[threadIdx.x - off] : 0;
        __syncthreads();
        s[threadIdx.x] += t;
        __syncthreads();
    }
    if (i < n) {
        int rs = s[threadIdx.x] - v + block_sums[blockIdx.x];
        row_start[i] = rs;
        cursor[i] = rs;
    }
    if (blockIdx.x == 0 && threadIdx.x == 0) row_start[n] = n_edges;
}

__global__ __launch_bounds__(256) void fill_part_kernel(
    const int* __restrict__ src, const int* __restrict__ dst,
    int* __restrict__ cursor, int* __restrict__ csr_src,
    int n_edges, int n_nodes)
{
    const int p      = blockIdx.x & (NPART - 1);
    const int chunk  = blockIdx.x >> 3;
    const int pstart = (int)(((long long)n_nodes * p)       / NPART);
    const int pend   = (int)(((long long)n_nodes * (p + 1)) / NPART);

    int e0 = chunk * (256 * 4) + threadIdx.x * 4;
    if (e0 >= n_edges) return;
    if (e0 + 3 < n_edges) {
        i32x4 d = __builtin_nontemporal_load((const i32x4*)(dst + e0));
        i32x4 s = __builtin_nontemporal_load((const i32x4*)(src + e0));
        if (d.x >= pstart && d.x < pend) csr_src[atomicAdd(&cursor[d.x], 1)] = s.x;
        if (d.y >= pstart && d.y < pend) csr_src[atomicAdd(&cursor[d.y], 1)] = s.y;
        if (d.z >= pstart && d.z < pend) csr_src[atomicAdd(&cursor[d.z], 1)] = s.z;
        if (d.w >= pstart && d.w < pend) csr_src[atomicAdd(&cursor[d.w], 1)] = s.w;
    } else {
        for (int e = e0; e < n_edges; ++e) {
            int d = dst[e];
            if (d >= pstart && d < pend) csr_src[atomicAdd(&cursor[d], 1)] = src[e];
        }
    }
}

// ---------------- gather aggregation (bf16 neighbors, fp32 self/acc) -------

__device__ __forceinline__ void add_row8(float acc[8], uint4 r) {
    union { unsigned u; float f; } c;
    c.u = r.x << 16;         acc[0] += c.f;
    c.u = r.x & 0xffff0000u; acc[1] += c.f;
    c.u = r.y << 16;         acc[2] += c.f;
    c.u = r.y & 0xffff0000u; acc[3] += c.f;
    c.u = r.z << 16;         acc[4] += c.f;
    c.u = r.z & 0xffff0000u; acc[5] += c.f;
    c.u = r.w << 16;         acc[6] += c.f;
    c.u = r.w & 0xffff0000u; acc[7] += c.f;
}

__global__ __launch_bounds__(256) void gather_agg_bf16_kernel(
    const float* __restrict__ xf,    // fp32 rows (self term)
    const uint4* __restrict__ xb,    // bf16 rows, 16 uint4/row
    const int* __restrict__ row_start, const int* __restrict__ csr_src,
    float* __restrict__ out, int n_nodes)
{
    int t = blockIdx.x * 256 + threadIdx.x;
    int node = t >> 4;
    int lane = t & 15;
    if (node >= n_nodes) return;
    int lo = row_start[node];
    int hi = row_start[node + 1];

    const f32x4* xfr = (const f32x4*)(xf + (size_t)node * IN_DIM + lane * 8);
    f32x4 a0 = __builtin_nontemporal_load(xfr);
    f32x4 a1 = __builtin_nontemporal_load(xfr + 1);
    float acc[8] = {a0.x, a0.y, a0.z, a0.w, a1.x, a1.y, a1.z, a1.w};

    int e = lo;
    for (; e + 3 < hi; e += 4) {
        int s0 = __builtin_nontemporal_load(csr_src + e);
        int s1 = __builtin_nontemporal_load(csr_src + e + 1);
        int s2 = __builtin_nontemporal_load(csr_src + e + 2);
        int s3 = __builtin_nontemporal_load(csr_src + e + 3);
        uint4 r0 = xb[(size_t)s0 * 16 + lane];
        uint4 r1 = xb[(size_t)s1 * 16 + lane];
        uint4 r2 = xb[(size_t)s2 * 16 + lane];
        uint4 r3 = xb[(size_t)s3 * 16 + lane];
        add_row8(acc, r0);
        add_row8(acc, r1);
        add_row8(acc, r2);
        add_row8(acc, r3);
    }
    for (; e < hi; ++e) {
        uint4 r = xb[(size_t)csr_src[e] * 16 + lane];
        add_row8(acc, r);
    }

    f32x4 o0 = {acc[0], acc[1], acc[2], acc[3]};
    f32x4 o1 = {acc[4], acc[5], acc[6], acc[7]};
    f32x4* op = (f32x4*)(out + (size_t)node * IN_DIM + lane * 8);
    __builtin_nontemporal_store(o0, op);
    __builtin_nontemporal_store(o1, op + 1);
}

// ---------------- split-bf16 MFMA GEMM -------------------------------------
// C[M x 128] = relu(A @ W + bias), via Ah@Wh + Al@Wh + Ah@Wl (fp32-accurate).
// Block 256 thr = 4 waves, 64 rows/block; wave w -> rows [w*16, w*16+16).
// LDS rows padded to 40 bf16 (80 B) -> 2-way banks (free). K chunked by 32.
__global__ __launch_bounds__(256) void gemm128_mfma_kernel(
    const float* __restrict__ A,
    const unsigned short* __restrict__ Wt_h,  // [n][k] bf16 hi
    const unsigned short* __restrict__ Wt_l,  // [n][k] bf16 lo
    const float* __restrict__ bias,
    float* __restrict__ C, int M)
{
    __shared__ __align__(16) unsigned short Ah[64][40];
    __shared__ __align__(16) unsigned short Al[64][40];
    __shared__ __align__(16) unsigned short Wh[128][40];
    __shared__ __align__(16) unsigned short Wl[128][40];

    const int t    = threadIdx.x;
    const int wave = t >> 6;
    const int lane = t & 63;
    const int l15  = lane & 15;
    const int quad = lane >> 4;
    const int row0 = blockIdx.x * 64;

    f32x4 acc[8];
#pragma unroll
    for (int ct = 0; ct < 8; ++ct) acc[ct] = {0.f, 0.f, 0.f, 0.f};

    // A staging coords: 8 consecutive fp32 along k per thread
    const int ar = (t * 8) >> 5;   // 0..63
    const int ak = (t * 8) & 31;   // 0,8,16,24
    const int arow = row0 + ar;
    const float* aptr = A + (size_t)((arow < M) ? arow : (M - 1)) * IN_DIM + ak;

    for (int k0 = 0; k0 < IN_DIM; k0 += 32) {
        // --- stage A (64 x 32 fp32 -> bf16 hi/lo)
        {
            float4 v0 = *(const float4*)(aptr + k0);
            float4 v1 = *(const float4*)(aptr + k0 + 4);
            float v[8] = {v0.x, v0.y, v0.z, v0.w, v1.x, v1.y, v1.z, v1.w};
            unsigned short h[8], l[8];
#pragma unroll
            for (int j = 0; j < 8; ++j) {
                unsigned short hh = bf16_rne(v[j]);
                float hf = __uint_as_float(((unsigned)hh) << 16);
                h[j] = hh;
                l[j] = bf16_rne(v[j] - hf);
            }
            *(uint4*)&Ah[ar][ak] = *(uint4*)h;
            *(uint4*)&Al[ar][ak] = *(uint4*)l;
        }
        // --- stage W chunk (128 n x 32 k bf16 hi/lo), 2 uint4 pairs/thread
        {
#pragma unroll
            for (int j = 0; j < 2; ++j) {
                int pos = t * 2 + j;            // 0..511
                int n   = pos >> 2;
                int k8  = (pos & 3) * 8;
                uint4 vh = *(const uint4*)(Wt_h + (size_t)n * IN_DIM + k0 + k8);
                uint4 vl = *(const uint4*)(Wt_l + (size_t)n * IN_DIM + k0 + k8);
                *(uint4*)&Wh[n][k8] = vh;
                *(uint4*)&Wl[n][k8] = vl;
            }
        }
        __syncthreads();

        // --- compute
        bf16x8 ah = *(const bf16x8*)&Ah[wave * 16 + l15][quad * 8];
        bf16x8 al = *(const bf16x8*)&Al[wave * 16 + l15][quad * 8];
#pragma unroll
        for (int ct = 0; ct < 8; ++ct) {
            bf16x8 wh = *(const bf16x8*)&Wh[ct * 16 + l15][quad * 8];
            bf16x8 wl = *(const bf16x8*)&Wl[ct * 16 + l15][quad * 8];
            acc[ct] = __builtin_amdgcn_mfma_f32_16x16x32_bf16(ah, wh, acc[ct], 0, 0, 0);
            acc[ct] = __builtin_amdgcn_mfma_f32_16x16x32_bf16(al, wh, acc[ct], 0, 0, 0);
            acc[ct] = __builtin_amdgcn_mfma_f32_16x16x32_bf16(ah, wl, acc[ct], 0, 0, 0);
        }
        __syncthreads();
    }

    // --- epilogue: bias + relu, C/D layout col=l15, row=quad*4+reg
    const int rbase = row0 + wave * 16 + quad * 4;
#pragma unroll
    for (int ct = 0; ct < 8; ++ct) {
        int col = ct * 16 + l15;
        float b = bias[col];
#pragma unroll
        for (int r = 0; r < 4; ++r) {
            int row = rbase + r;
            if (row < M)
                C[(size_t)row * IN_DIM + col] = fmaxf(acc[ct][r] + b, 0.f);
        }
    }
}

// ---------------- pool + heads ---------------------------------------------

__device__ __forceinline__ int lower_bound_i(const int* __restrict__ a, int n, int v) {
    int lo = 0, hi = n;
    while (lo < hi) {
        int mid = (lo + hi) >> 1;
        if (a[mid] < v) lo = mid + 1; else hi = mid;
    }
    return lo;
}

__global__ __launch_bounds__(128) void pool_kernel(
    const float* __restrict__ h, const int* __restrict__ batch,
    float* __restrict__ pooled, int n_nodes, int n_graphs)
{
    int g = blockIdx.x;
    int lo = lower_bound_i(batch, n_nodes, g);
    int hi = lower_bound_i(batch, n_nodes, g + 1);
    int j = threadIdx.x;
    float acc = 0.f;
    for (int i = lo; i < hi; ++i)
        acc += h[(size_t)i * IN_DIM + j];
    float cnt = (float)(hi - lo);
    pooled[(size_t)g * IN_DIM + j] = acc / fmaxf(cnt, 1.0f);
}

__global__ __launch_bounds__(64) void head_kernel(
    const float* __restrict__ pooled,
    const float* __restrict__ Ws,  const float* __restrict__ bs,
    const float* __restrict__ WlS, const float* __restrict__ blS,
    const float* __restrict__ WlP, const float* __restrict__ blP,
    const float* __restrict__ WnR, const float* __restrict__ bnR,
    float* __restrict__ out, int n_graphs)
{
    int g = blockIdx.x;
    int j = threadIdx.x;
    const float* p = pooled + (size_t)g * IN_DIM;
    float acc = bs[j];
#pragma unroll 8
    for (int k = 0; k < IN_DIM; ++k)
        acc = fmaf(p[k], Ws[k * 64 + j], acc);
    float gj = fmaxf(acc, 0.f);
    float s1 = gj * WlS[j];
    float s2 = gj * WlP[j];
    float s3 = gj * WnR[j];
#pragma unroll
    for (int off = 32; off > 0; off >>= 1) {
        s1 += __shfl_down(s1, off);
        s2 += __shfl_down(s2, off);
        s3 += __shfl_down(s3, off);
    }
    if (j == 0) {
        out[g]                = s1 + blS[0];
        out[n_graphs + g]     = s2 + blP[0];
        out[2 * n_graphs + g] = s3 + bnR[0];
    }
}

// ---------------- launch ---------------------------------------------------

extern "C" void kernel_launch(void* const* d_in, const int* in_sizes, int n_in,
                              void* d_out, int out_size, void* d_ws, size_t ws_size,
                              hipStream_t stream)
{
    const float* x   = (const float*)d_in[0];
    const int*   ei  = (const int*)d_in[1];
    const int*   bat = (const int*)d_in[2];
    const float* W1a = (const float*)d_in[3];
    const float* b1a = (const float*)d_in[4];
    const float* W1b = (const float*)d_in[5];
    const float* b1b = (const float*)d_in[6];
    const float* W2a = (const float*)d_in[7];
    const float* b2a = (const float*)d_in[8];
    const float* W2b = (const float*)d_in[9];
    const float* b2b = (const float*)d_in[10];
    const float* Ws  = (const float*)d_in[11];
    const float* bs  = (const float*)d_in[12];
    const float* WlS = (const float*)d_in[13];
    const float* blS = (const float*)d_in[14];
    const float* WlP = (const float*)d_in[15];
    const float* blP = (const float*)d_in[16];
    const float* WnR = (const float*)d_in[17];
    const float* bnR = (const float*)d_in[18];

    const int n_nodes  = in_sizes[0] / IN_DIM;
    const int n_edges  = in_sizes[1] / 2;
    const int n_graphs = out_size / 3;
    const int* src = ei;
    const int* dst = ei + n_edges;

    const size_t node_elems   = (size_t)n_nodes * IN_DIM;
    const size_t pooled_elems = (size_t)n_graphs * IN_DIM;

    float* h1     = (float*)d_ws;
    float* buf2   = h1   + node_elems;
    float* bufA   = buf2 + node_elems;          // gather output (x + agg)
    float* pooled = bufA + node_elems;
    int* row_start = (int*)(pooled + pooled_elems);   // n_nodes + 1
    int* cursor    = row_start + (n_nodes + 1);       // n_nodes (also histogram)
    int* csr_src   = cursor + n_nodes;                // n_edges
    unsigned short* wt_h = (unsigned short*)(csr_src + n_edges);  // 4 * 16384
    unsigned short* wt_l = wt_h + 4 * 16384;

    // bf16 mirror aliases h1 (dead at convert time; consumed before h1 write)
    uint4* xb = (uint4*)h1;

    const int eblocks4 = (n_edges + 1023) / 1024;
    const int nblocks256 = (n_nodes + 255) / 256;
    const int gatherblocks = (int)(((size_t)n_nodes * 16 + 255) / 256);
    const int gemmblocks = (n_nodes + 63) / 64;
    const int partblocks = NPART * eblocks4;
    const int n8 = (int)(node_elems / 8);
    const int cvtblocks = (n8 + 255) / 256;

    // ---- weight conversion + CSR build ----
    conv_weights_kernel<<<256, 256, 0, stream>>>(W1a, W1b, W2a, W2b, wt_h, wt_l);
    hipMemsetAsync(cursor, 0, (size_t)n_nodes * sizeof(int), stream);
    hist_part_kernel<<<partblocks, 256, 0, stream>>>(dst, cursor, n_edges, n_nodes);
    scan_phaseA<<<nblocks256, 256, 0, stream>>>(cursor, csr_src /*scratch*/, n_nodes);
    scan_phaseB<<<1, 256, 0, stream>>>(csr_src, nblocks256);
    scan_phaseC<<<nblocks256, 256, 0, stream>>>(cursor, csr_src, row_start,
                                                cursor, n_nodes, n_edges);
    fill_part_kernel<<<partblocks, 256, 0, stream>>>(src, dst, cursor, csr_src,
                                                     n_edges, n_nodes);

    // ---- layer 1 ----
    f32_to_bf16_kernel<<<cvtblocks, 256, 0, stream>>>((const float4*)x, xb, n8);
    gather_agg_bf16_kernel<<<gatherblocks, 256, 0, stream>>>(
        x, xb, row_start, csr_src, bufA, n_nodes);
    gemm128_mfma_kernel<<<gemmblocks, 256, 0, stream>>>(
        bufA, wt_h,             wt_l,             b1a, h1,   n_nodes);
    gemm128_mfma_kernel<<<gemmblocks, 256, 0, stream>>>(
        h1,   wt_h + 16384,     wt_l + 16384,     b1b, buf2, n_nodes);

    // ---- layer 2 ----
    f32_to_bf16_kernel<<<cvtblocks, 256, 0, stream>>>((const float4*)buf2, xb, n8);
    gather_agg_bf16_kernel<<<gatherblocks, 256, 0, stream>>>(
        buf2, xb, row_start, csr_src, bufA, n_nodes);
    gemm128_mfma_kernel<<<gemmblocks, 256, 0, stream>>>(
        bufA, wt_h + 2 * 16384, wt_l + 2 * 16384, b2a, h1,   n_nodes);
    gemm128_mfma_kernel<<<gemmblocks, 256, 0, stream>>>(
        h1,   wt_h + 3 * 16384, wt_l + 3 * 16384, b2b, buf2, n_nodes);

    // ---- pool + heads ----
    pool_kernel<<<n_graphs, 128, 0, stream>>>(buf2, bat, pooled, n_nodes, n_graphs);
    head_kernel<<<n_graphs, 64, 0, stream>>>(pooled, Ws, bs, WlS, blS, WlP, blP,
                                             WnR, bnR, (float*)d_out, n_graphs);
}